// Round 1
// baseline (412.637 us; speedup 1.0000x reference)
//
#include <hip/hip_runtime.h>

#define BATCH 8
#define DIN   512
#define SEQ   8192
#define ECH   1024   // concatenated conv output channels (fore 512 | back 512)
#define HCH   256    // per-direction hidden channels
#define CL    32     // scan chunk length
#define NCHNK (SEQ / CL)   // 256 chunks per row

typedef __bf16 bf16;
typedef __bf16 bf16x8 __attribute__((ext_vector_type(8)));
typedef __bf16 bf16x4 __attribute__((ext_vector_type(4)));
typedef float  floatx4 __attribute__((ext_vector_type(4)));

__device__ __forceinline__ void async_ld16(void* lds, const void* g) {
  __builtin_amdgcn_global_load_lds(
      (const __attribute__((address_space(1))) unsigned int*)g,
      (__attribute__((address_space(3))) unsigned int*)lds, 16, 0, 0);
}

__device__ __forceinline__ float bits2f(unsigned u) {
  return __builtin_bit_cast(float, u);
}

// ---------------------------------------------------------------------------
// Kernel 1: convert/permute weights to bf16, channel-interleaved (h,gate) pairs.
// Wb row n: dir = n>>9, r = n&511, e = r>>1, isg = r&1 -> source channel e + isg*256.
// ---------------------------------------------------------------------------
__global__ void k_wconv(const float* __restrict__ wf, const float* __restrict__ bfo,
                        const float* __restrict__ wb, const float* __restrict__ bb,
                        bf16* __restrict__ Wb, float* __restrict__ bias) {
  int idx = blockIdx.x * 256 + threadIdx.x;
  if (idx < ECH * DIN) {
    int n = idx >> 9, d = idx & 511;
    int dir = n >> 9, r = n & 511, e = r >> 1, isg = r & 1;
    int s = e + (isg ? HCH : 0);
    const float* w = dir ? wb : wf;
    Wb[idx] = (bf16)w[s * DIN + d];
  }
  if (idx < ECH) {
    int dir = idx >> 9, r = idx & 511, e = r >> 1, isg = r & 1;
    int s = e + (isg ? HCH : 0);
    bias[idx] = (dir ? bb : bfo)[s];
  }
}

// ---------------------------------------------------------------------------
// Kernel 2: tiled transpose + convert  x[b,d,l] fp32 -> xT[b,l,d] bf16
// 64x64 tiles via LDS (pad 65 to break bank conflicts).
// ---------------------------------------------------------------------------
__global__ void k_xpose(const float* __restrict__ x, bf16* __restrict__ xT) {
  __shared__ float T[64 * 65];
  int t = threadIdx.x;
  int l0 = blockIdx.x * 64;
  int d0 = blockIdx.y * 64;
  int b  = blockIdx.z;
  const float* xb = x + (size_t)b * DIN * SEQ;
#pragma unroll
  for (int p = 0; p < 4; ++p) {
    int dl = (t >> 4) + p * 16;
    int l4 = (t & 15) * 4;
    float4 v = *(const float4*)(xb + (size_t)(d0 + dl) * SEQ + l0 + l4);
    T[dl * 65 + l4 + 0] = v.x;
    T[dl * 65 + l4 + 1] = v.y;
    T[dl * 65 + l4 + 2] = v.z;
    T[dl * 65 + l4 + 3] = v.w;
  }
  __syncthreads();
  bf16* xTb = xT + (size_t)b * SEQ * DIN;
#pragma unroll
  for (int p = 0; p < 4; ++p) {
    int ll = (t >> 4) + p * 16;
    int d4 = (t & 15) * 4;
    bf16x4 h;
#pragma unroll
    for (int j = 0; j < 4; ++j) h[j] = (bf16)T[(d4 + j) * 65 + ll];
    *(bf16x4*)(xTb + (size_t)(l0 + ll) * DIN + d0 + d4) = h;
  }
}

// ---------------------------------------------------------------------------
// Kernel 3: bf16 MFMA GEMM  hg[b,l,n] = sum_d xT[b,l,d] * Wb[n,d] + bias[n]
// 128x128 block tile, BK=64, 4 waves (2x2), each wave 64x64 = 4x4 16x16x32 frags.
// Staging via global_load_lds width 16 (m97 structure). C through LDS -> coalesced.
// ---------------------------------------------------------------------------
__launch_bounds__(256, 2)
__global__ void k_gemm(const bf16* __restrict__ xT, const bf16* __restrict__ Wb,
                       const float* __restrict__ bias, bf16* __restrict__ hg) {
  __shared__ bf16 lds[16384];       // As[128][64] | Bs[128][64]; reused as Cs[128][128]
  bf16* As = lds;
  bf16* Bs = lds + 8192;

  int t = threadIdx.x;
  int lane = t & 63, wave = t >> 6;
  int n0 = blockIdx.x * 128;
  int l0 = blockIdx.y * 128;
  int b  = blockIdx.z;
  int l15 = lane & 15, quad = lane >> 4;
  int wm = wave >> 1, wn = wave & 1;
  int mb = wm * 64, nb = wn * 64;

  const bf16* gA = xT + ((size_t)b * SEQ + l0) * DIN;
  const bf16* gB = Wb + (size_t)n0 * DIN;

  int srow = wave * 32 + (lane >> 3);   // + q*8 later
  int scol = (lane & 7) * 8;

  floatx4 acc[4][4];
#pragma unroll
  for (int i = 0; i < 4; ++i)
#pragma unroll
    for (int j = 0; j < 4; ++j) acc[i][j] = (floatx4){0.f, 0.f, 0.f, 0.f};

  for (int kt = 0; kt < DIN / 64; ++kt) {
    int k0 = kt * 64;
#pragma unroll
    for (int q = 0; q < 4; ++q) {
      async_ld16(As + (wave * 32 + q * 8) * 64,
                 gA + (size_t)(srow + q * 8) * DIN + k0 + scol);
      async_ld16(Bs + (wave * 32 + q * 8) * 64,
                 gB + (size_t)(srow + q * 8) * DIN + k0 + scol);
    }
    __syncthreads();
#pragma unroll
    for (int kk = 0; kk < 64; kk += 32) {
      bf16x8 af[4], bfr[4];
#pragma unroll
      for (int i = 0; i < 4; ++i)
        af[i] = *(const bf16x8*)(As + (mb + i * 16 + l15) * 64 + kk + quad * 8);
#pragma unroll
      for (int i = 0; i < 4; ++i)
        bfr[i] = *(const bf16x8*)(Bs + (nb + i * 16 + l15) * 64 + kk + quad * 8);
#pragma unroll
      for (int mi = 0; mi < 4; ++mi)
#pragma unroll
        for (int ni = 0; ni < 4; ++ni)
          acc[mi][ni] = __builtin_amdgcn_mfma_f32_16x16x32_bf16(
              af[mi], bfr[ni], acc[mi][ni], 0, 0, 0);
    }
    __syncthreads();
  }

  // epilogue: bias add, pack to bf16 in LDS, coalesced store
  float bb4[4];
#pragma unroll
  for (int ni = 0; ni < 4; ++ni) bb4[ni] = bias[n0 + nb + ni * 16 + l15];
  bf16* Cs = lds;  // [128][128]
#pragma unroll
  for (int mi = 0; mi < 4; ++mi)
#pragma unroll
    for (int ni = 0; ni < 4; ++ni)
#pragma unroll
      for (int r = 0; r < 4; ++r) {
        int row = mb + mi * 16 + quad * 4 + r;
        int col = nb + ni * 16 + l15;
        Cs[row * 128 + col] = (bf16)(acc[mi][ni][r] + bb4[ni]);
      }
  __syncthreads();
  bf16* hgb = hg + ((size_t)b * SEQ + l0) * ECH + n0;
#pragma unroll
  for (int p = 0; p < 8; ++p) {
    int row = p * 16 + (t >> 4);
    int seg = t & 15;
    *(bf16x8*)(hgb + (size_t)row * ECH + seg * 8) =
        *(const bf16x8*)(Cs + row * 128 + seg * 8);
  }
}

// ---------------------------------------------------------------------------
// minGRU step math: given packed (h,gate) bf16 pair in a uint:
//   a = sigmoid(-g), bt = sigmoid(g) * (h>=0 ? 1+h : exp(h))
// ---------------------------------------------------------------------------
__device__ __forceinline__ void gru_ab(unsigned v, float& a, float& bt) {
  float hh = bits2f(v << 16);
  float g  = bits2f(v & 0xffff0000u);
  float eg = __expf(-g);
  float sg = 1.f / (1.f + eg);   // sigmoid(g)
  a = eg * sg;                    // sigmoid(-g)
  float gv = hh >= 0.f ? 1.f + hh : __expf(hh);
  bt = sg * gv;
}

// ---------------------------------------------------------------------------
// Kernel 4: per-chunk affine composition (A, B). Block = (chunk, dir, b), 256 e.
// ---------------------------------------------------------------------------
__global__ void k_scan1(const bf16* __restrict__ hg, float* __restrict__ Asum,
                        float* __restrict__ Bsum) {
  int t = threadIdx.x;
  int chunk = blockIdx.x, dir = blockIdx.y, b = blockIdx.z;
  const bf16* hb = hg + (size_t)b * SEQ * ECH + dir * 512 + 2 * t;
  float A = 1.f, Bc = 0.f;
  int lbase = chunk * CL;
#pragma unroll 8
  for (int i = 0; i < CL; ++i) {
    int l = dir ? (lbase + CL - 1 - i) : (lbase + i);
    unsigned v = *(const unsigned*)(hb + (size_t)l * ECH);
    float a, bt;
    gru_ab(v, a, bt);
    A *= a;
    Bc = a * Bc + bt;
  }
  size_t o = ((size_t)(b * 2 + dir) * NCHNK + chunk) * 256 + t;
  Asum[o] = A;
  Bsum[o] = Bc;
}

// ---------------------------------------------------------------------------
// Kernel 5: scan chunk summaries per row -> carry-in h for each chunk.
// ---------------------------------------------------------------------------
__global__ void k_scan2(const float* __restrict__ Asum, const float* __restrict__ Bsum,
                        float* __restrict__ hin) {
  int tid = blockIdx.x * 256 + threadIdx.x;  // 4096 rows
  int b = tid >> 9, dir = (tid >> 8) & 1, e = tid & 255;
  size_t rb = (size_t)(b * 2 + dir) * NCHNK;
  float h = 0.f;
  if (dir == 0) {
    for (int c = 0; c < NCHNK; ++c) {
      size_t o = (rb + c) * 256 + e;
      hin[o] = h;
      h = Asum[o] * h + Bsum[o];
    }
  } else {
    for (int c = NCHNK - 1; c >= 0; --c) {
      size_t o = (rb + c) * 256 + e;
      hin[o] = h;
      h = Asum[o] * h + Bsum[o];
    }
  }
}

// ---------------------------------------------------------------------------
// Kernel 6: recompute local scan with carry-in, transpose via LDS (stride 33),
// write out[b, dir*256+e, l] as coalesced float4.
// ---------------------------------------------------------------------------
__global__ void k_scan3(const bf16* __restrict__ hg, const float* __restrict__ hin,
                        float* __restrict__ out) {
  __shared__ float T[256 * 33];
  int t = threadIdx.x;
  int chunk = blockIdx.x, dir = blockIdx.y, b = blockIdx.z;
  const bf16* hb = hg + (size_t)b * SEQ * ECH + dir * 512 + 2 * t;
  float h = hin[((size_t)(b * 2 + dir) * NCHNK + chunk) * 256 + t];
  int lbase = chunk * CL;
#pragma unroll 8
  for (int i = 0; i < CL; ++i) {
    int ll = dir ? (CL - 1 - i) : i;
    unsigned v = *(const unsigned*)(hb + (size_t)(lbase + ll) * ECH);
    float a, bt;
    gru_ab(v, a, bt);
    h = a * h + bt;
    T[t * 33 + ll] = h;
  }
  __syncthreads();
  float* ob = out + ((size_t)b * 512 + dir * 256) * SEQ + lbase;
#pragma unroll
  for (int p = 0; p < 8; ++p) {
    int row = p * 32 + (t >> 3);   // e channel
    int c4 = (t & 7) * 4;          // l within chunk
    float4 v4;
    v4.x = T[row * 33 + c4 + 0];
    v4.y = T[row * 33 + c4 + 1];
    v4.z = T[row * 33 + c4 + 2];
    v4.w = T[row * 33 + c4 + 3];
    *(float4*)(ob + (size_t)row * SEQ + c4) = v4;
  }
}

// ---------------------------------------------------------------------------
extern "C" void kernel_launch(void* const* d_in, const int* in_sizes, int n_in,
                              void* d_out, int out_size, void* d_ws, size_t ws_size,
                              hipStream_t stream) {
  const float* x   = (const float*)d_in[0];
  const float* wf  = (const float*)d_in[1];
  const float* bfo = (const float*)d_in[2];
  const float* wb  = (const float*)d_in[3];
  const float* bb  = (const float*)d_in[4];
  float* out = (float*)d_out;
  char* ws = (char*)d_ws;

  // workspace layout (bytes):
  bf16*  xT   = (bf16*)(ws);                       // 67,108,864
  bf16*  hg   = (bf16*)(ws + 67108864);            // 134,217,728
  bf16*  Wbm  = (bf16*)(ws + 201326592);           // 1,048,576
  float* bias = (float*)(ws + 202375168);          // 4,096
  float* Asum = (float*)(ws + 202379264);          // 4,194,304
  float* Bsum = (float*)(ws + 206573568);          // 4,194,304
  float* hin  = (float*)(ws + 210767872);          // 4,194,304  (total ~215 MB)

  k_wconv<<<2048, 256, 0, stream>>>(wf, bfo, wb, bb, Wbm, bias);
  k_xpose<<<dim3(SEQ / 64, DIN / 64, BATCH), 256, 0, stream>>>(x, xT);
  k_gemm<<<dim3(ECH / 128, SEQ / 128, BATCH), 256, 0, stream>>>(xT, Wbm, bias, hg);
  k_scan1<<<dim3(NCHNK, 2, BATCH), 256, 0, stream>>>(hg, Asum, Bsum);
  k_scan2<<<16, 256, 0, stream>>>(Asum, Bsum, hin);
  k_scan3<<<dim3(NCHNK, 2, BATCH), 256, 0, stream>>>(hg, hin, out);
}

// Round 2
// 387.301 us; speedup vs baseline: 1.0654x; 1.0654x over previous
//
#include <hip/hip_runtime.h>

#define BATCH 8
#define DIN   512
#define SEQ   8192
#define ECH   1024   // concatenated conv output channels (fore 512 | back 512)
#define HCH   256    // per-direction hidden channels
#define CL    32     // scan chunk length
#define NCHNK (SEQ / CL)   // 256 chunks per row
#define NSC   16           // superchunks (16 chunks each)

typedef __bf16 bf16;
typedef __bf16 bf16x8 __attribute__((ext_vector_type(8)));
typedef __bf16 bf16x4 __attribute__((ext_vector_type(4)));
typedef float  floatx4 __attribute__((ext_vector_type(4)));

__device__ __forceinline__ void async_ld16(void* lds, const void* g) {
  __builtin_amdgcn_global_load_lds(
      (const __attribute__((address_space(1))) unsigned int*)g,
      (__attribute__((address_space(3))) unsigned int*)lds, 16, 0, 0);
}

__device__ __forceinline__ float bits2f(unsigned u) {
  return __builtin_bit_cast(float, u);
}

// ---------------------------------------------------------------------------
// Kernel 1: convert/permute weights to bf16, channel-interleaved (h,gate) pairs.
// ---------------------------------------------------------------------------
__global__ void k_wconv(const float* __restrict__ wf, const float* __restrict__ bfo,
                        const float* __restrict__ wb, const float* __restrict__ bb,
                        bf16* __restrict__ Wb, float* __restrict__ bias) {
  int idx = blockIdx.x * 256 + threadIdx.x;
  if (idx < ECH * DIN) {
    int n = idx >> 9, d = idx & 511;
    int dir = n >> 9, r = n & 511, e = r >> 1, isg = r & 1;
    int s = e + (isg ? HCH : 0);
    const float* w = dir ? wb : wf;
    Wb[idx] = (bf16)w[s * DIN + d];
  }
  if (idx < ECH) {
    int dir = idx >> 9, r = idx & 511, e = r >> 1, isg = r & 1;
    int s = e + (isg ? HCH : 0);
    bias[idx] = (dir ? bb : bfo)[s];
  }
}

// ---------------------------------------------------------------------------
// Kernel 2: tiled transpose + convert  x[b,d,l] fp32 -> xT[b,l,d] bf16
// ---------------------------------------------------------------------------
__global__ void k_xpose(const float* __restrict__ x, bf16* __restrict__ xT) {
  __shared__ float T[64 * 65];
  int t = threadIdx.x;
  int l0 = blockIdx.x * 64;
  int d0 = blockIdx.y * 64;
  int b  = blockIdx.z;
  const float* xb = x + (size_t)b * DIN * SEQ;
#pragma unroll
  for (int p = 0; p < 4; ++p) {
    int dl = (t >> 4) + p * 16;
    int l4 = (t & 15) * 4;
    float4 v = *(const float4*)(xb + (size_t)(d0 + dl) * SEQ + l0 + l4);
    T[dl * 65 + l4 + 0] = v.x;
    T[dl * 65 + l4 + 1] = v.y;
    T[dl * 65 + l4 + 2] = v.z;
    T[dl * 65 + l4 + 3] = v.w;
  }
  __syncthreads();
  bf16* xTb = xT + (size_t)b * SEQ * DIN;
#pragma unroll
  for (int p = 0; p < 2; ++p) {
    int ll = (t >> 3) + p * 32;
    int d8 = (t & 7) * 8;
    bf16x8 h;
#pragma unroll
    for (int j = 0; j < 8; ++j) h[j] = (bf16)T[(d8 + j) * 65 + ll];
    *(bf16x8*)(xTb + (size_t)(l0 + ll) * DIN + d0 + d8) = h;
  }
}

// ---------------------------------------------------------------------------
// Kernel 3: bf16 MFMA GEMM  hg[b,l,n] = sum_d xT[b,l,d] * Wb[n,d] + bias[n]
// 128x128 tile, BK=64, 4 waves, 16x16x32 frags. XOR-swizzled LDS (kills the
// 16-way ds_read conflict); XCD-locality block remap (all 8 n-tiles of an
// l-tile on one XCD -> A fetched ~once from HBM).
// ---------------------------------------------------------------------------
__launch_bounds__(256, 2)
__global__ void k_gemm(const bf16* __restrict__ xT, const bf16* __restrict__ Wb,
                       const float* __restrict__ bias, bf16* __restrict__ hg) {
  __shared__ bf16 lds[16896];       // staging: As[128][64]|Bs[128][64]; epilogue: Cs[128][132]
  bf16* As = lds;
  bf16* Bs = lds + 8192;

  int t = threadIdx.x;
  int lane = t & 63, wave = t >> 6;

  // XCD-locality remap: lin%8 == XCD (round-robin heuristic). Give each XCD
  // whole l-tiles (all 8 n-tiles) so the A-tile is fetched once per chip.
  int lin = blockIdx.x + 8 * blockIdx.y;   // 0..511
  int xcd = lin & 7;
  int seq = lin >> 3;                      // 0..63
  int ltile = xcd + 8 * (seq >> 3);        // 0..63
  int ntile = seq & 7;
  int n0 = ntile * 128;
  int l0 = ltile * 128;
  int b  = blockIdx.z;

  int l15 = lane & 15, quad = lane >> 4;
  int wm = wave >> 1, wn = wave & 1;
  int mb = wm * 64, nb = wn * 64;

  const bf16* gA = xT + ((size_t)b * SEQ + l0) * DIN;
  const bf16* gB = Wb + (size_t)n0 * DIN;

  int srow = wave * 32 + (lane >> 3);                       // + q*8 later
  int scol = (((lane & 7) ^ (lane >> 3)) * 8);              // XOR-swizzled source col

  floatx4 acc[4][4];
#pragma unroll
  for (int i = 0; i < 4; ++i)
#pragma unroll
    for (int j = 0; j < 4; ++j) acc[i][j] = (floatx4){0.f, 0.f, 0.f, 0.f};

  for (int kt = 0; kt < DIN / 64; ++kt) {
    int k0 = kt * 64;
#pragma unroll
    for (int q = 0; q < 4; ++q) {
      async_ld16(As + (wave * 32 + q * 8) * 64,
                 gA + (size_t)(srow + q * 8) * DIN + k0 + scol);
      async_ld16(Bs + (wave * 32 + q * 8) * 64,
                 gB + (size_t)(srow + q * 8) * DIN + k0 + scol);
    }
    __syncthreads();
#pragma unroll
    for (int kk = 0; kk < 64; kk += 32) {
      int rsw = l15 & 7;
      bf16x8 af[4], bfr[4];
#pragma unroll
      for (int i = 0; i < 4; ++i)
        af[i] = *(const bf16x8*)(As + (mb + i * 16 + l15) * 64 +
                                 (((kk >> 3) + quad) ^ rsw) * 8);
#pragma unroll
      for (int i = 0; i < 4; ++i)
        bfr[i] = *(const bf16x8*)(Bs + (nb + i * 16 + l15) * 64 +
                                  (((kk >> 3) + quad) ^ rsw) * 8);
#pragma unroll
      for (int mi = 0; mi < 4; ++mi)
#pragma unroll
        for (int ni = 0; ni < 4; ++ni)
          acc[mi][ni] = __builtin_amdgcn_mfma_f32_16x16x32_bf16(
              af[mi], bfr[ni], acc[mi][ni], 0, 0, 0);
    }
    __syncthreads();
  }

  // epilogue: bias add, pack to bf16 in LDS (stride 132 breaks conflicts), store
  float bb4[4];
#pragma unroll
  for (int ni = 0; ni < 4; ++ni) bb4[ni] = bias[n0 + nb + ni * 16 + l15];
  bf16* Cs = lds;  // [128][132]
#pragma unroll
  for (int mi = 0; mi < 4; ++mi)
#pragma unroll
    for (int ni = 0; ni < 4; ++ni)
#pragma unroll
      for (int r = 0; r < 4; ++r) {
        int row = mb + mi * 16 + quad * 4 + r;
        int col = nb + ni * 16 + l15;
        Cs[row * 132 + col] = (bf16)(acc[mi][ni][r] + bb4[ni]);
      }
  __syncthreads();
  bf16* hgb = hg + ((size_t)b * SEQ + l0) * ECH + n0;
#pragma unroll
  for (int p = 0; p < 8; ++p) {
    int row = p * 16 + (t >> 4);
    int seg = t & 15;
    *(bf16x8*)(hgb + (size_t)row * ECH + seg * 8) =
        *(const bf16x8*)(Cs + row * 132 + seg * 8);
  }
}

// ---------------------------------------------------------------------------
// minGRU step: a = sigmoid(-g), bt = sigmoid(g) * (h>=0 ? 1+h : exp(h))
// ---------------------------------------------------------------------------
__device__ __forceinline__ void gru_ab(unsigned v, float& a, float& bt) {
  float hh = bits2f(v << 16);
  float g  = bits2f(v & 0xffff0000u);
  float eg = __expf(-g);
  float sg = 1.f / (1.f + eg);   // sigmoid(g)
  a = eg * sg;                    // sigmoid(-g)
  float gv = hh >= 0.f ? 1.f + hh : __expf(hh);
  bt = sg * gv;
}

// ---------------------------------------------------------------------------
// Kernel 4: per-chunk affine composition (A, B).
// ---------------------------------------------------------------------------
__global__ void k_scan1(const bf16* __restrict__ hg, float* __restrict__ Asum,
                        float* __restrict__ Bsum) {
  int t = threadIdx.x;
  int chunk = blockIdx.x, dir = blockIdx.y, b = blockIdx.z;
  const bf16* hb = hg + (size_t)b * SEQ * ECH + dir * 512 + 2 * t;
  float A = 1.f, Bc = 0.f;
  int lbase = chunk * CL;
#pragma unroll 8
  for (int i = 0; i < CL; ++i) {
    int l = dir ? (lbase + CL - 1 - i) : (lbase + i);
    unsigned v = *(const unsigned*)(hb + (size_t)l * ECH);
    float a, bt;
    gru_ab(v, a, bt);
    A *= a;
    Bc = a * Bc + bt;
  }
  size_t o = ((size_t)(b * 2 + dir) * NCHNK + chunk) * 256 + t;
  Asum[o] = A;
  Bsum[o] = Bc;
}

// ---------------------------------------------------------------------------
// Kernel 5a: per-superchunk (16 chunks) composition. 256 blocks x 256 thr.
// ---------------------------------------------------------------------------
__global__ void k_scan2a(const float* __restrict__ Asum, const float* __restrict__ Bsum,
                         float* __restrict__ SA, float* __restrict__ SB) {
  int e = threadIdx.x, sc = blockIdx.x, row2 = blockIdx.y, dir = row2 & 1;
  size_t base = (size_t)row2 * NCHNK;
  float Acc = 1.f, Bcc = 0.f;
#pragma unroll
  for (int i = 0; i < 16; ++i) {
    int c = sc * 16 + (dir ? 15 - i : i);
    size_t o = (base + c) * 256 + e;
    float a = Asum[o], bv = Bsum[o];
    Acc = a * Acc;
    Bcc = a * Bcc + bv;
  }
  size_t so = ((size_t)row2 * NSC + sc) * 256 + e;
  SA[so] = Acc;
  SB[so] = Bcc;
}

// ---------------------------------------------------------------------------
// Kernel 5b: scan the 16 superchunks per row. 16 blocks x 256 thr.
// ---------------------------------------------------------------------------
__global__ void k_scan2b(const float* __restrict__ SA, const float* __restrict__ SB,
                         float* __restrict__ hsc) {
  int e = threadIdx.x, row2 = blockIdx.x, dir = row2 & 1;
  float h = 0.f;
  for (int i = 0; i < NSC; ++i) {
    int sc = dir ? NSC - 1 - i : i;
    size_t o = ((size_t)row2 * NSC + sc) * 256 + e;
    hsc[o] = h;
    h = SA[o] * h + SB[o];
  }
}

// ---------------------------------------------------------------------------
// Kernel 5c: distribute carries to every chunk. 256 blocks x 256 thr.
// ---------------------------------------------------------------------------
__global__ void k_scan2c(const float* __restrict__ Asum, const float* __restrict__ Bsum,
                         const float* __restrict__ hsc, float* __restrict__ hin) {
  int e = threadIdx.x, sc = blockIdx.x, row2 = blockIdx.y, dir = row2 & 1;
  float h = hsc[((size_t)row2 * NSC + sc) * 256 + e];
#pragma unroll
  for (int i = 0; i < 16; ++i) {
    int c = sc * 16 + (dir ? 15 - i : i);
    size_t o = ((size_t)row2 * NCHNK + c) * 256 + e;
    hin[o] = h;
    h = Asum[o] * h + Bsum[o];
  }
}

// ---------------------------------------------------------------------------
// Kernel 6: recompute local scan with carry-in, transpose via LDS (stride 33),
// write out[b, dir*256+e, l] as coalesced float4.
// ---------------------------------------------------------------------------
__global__ void k_scan3(const bf16* __restrict__ hg, const float* __restrict__ hin,
                        float* __restrict__ out) {
  __shared__ float T[256 * 33];
  int t = threadIdx.x;
  int chunk = blockIdx.x, dir = blockIdx.y, b = blockIdx.z;
  const bf16* hb = hg + (size_t)b * SEQ * ECH + dir * 512 + 2 * t;
  float h = hin[((size_t)(b * 2 + dir) * NCHNK + chunk) * 256 + t];
  int lbase = chunk * CL;
#pragma unroll 8
  for (int i = 0; i < CL; ++i) {
    int ll = dir ? (CL - 1 - i) : i;
    unsigned v = *(const unsigned*)(hb + (size_t)(lbase + ll) * ECH);
    float a, bt;
    gru_ab(v, a, bt);
    h = a * h + bt;
    T[t * 33 + ll] = h;
  }
  __syncthreads();
  float* ob = out + ((size_t)b * 512 + dir * 256) * SEQ + lbase;
#pragma unroll
  for (int p = 0; p < 8; ++p) {
    int row = p * 32 + (t >> 3);   // e channel
    int c4 = (t & 7) * 4;          // l within chunk
    float4 v4;
    v4.x = T[row * 33 + c4 + 0];
    v4.y = T[row * 33 + c4 + 1];
    v4.z = T[row * 33 + c4 + 2];
    v4.w = T[row * 33 + c4 + 3];
    *(float4*)(ob + (size_t)row * SEQ + c4) = v4;
  }
}

// ---------------------------------------------------------------------------
extern "C" void kernel_launch(void* const* d_in, const int* in_sizes, int n_in,
                              void* d_out, int out_size, void* d_ws, size_t ws_size,
                              hipStream_t stream) {
  const float* x   = (const float*)d_in[0];
  const float* wf  = (const float*)d_in[1];
  const float* bfo = (const float*)d_in[2];
  const float* wb  = (const float*)d_in[3];
  const float* bb  = (const float*)d_in[4];
  float* out = (float*)d_out;
  char* ws = (char*)d_ws;

  // workspace layout (bytes):
  bf16*  xT   = (bf16*)(ws);                       // 67,108,864
  bf16*  hg   = (bf16*)(ws + 67108864);            // 134,217,728
  bf16*  Wbm  = (bf16*)(ws + 201326592);           // 1,048,576
  float* bias = (float*)(ws + 202375168);          // 4,096
  float* Asum = (float*)(ws + 202379264);          // 4,194,304
  float* Bsum = (float*)(ws + 206573568);          // 4,194,304
  float* hin  = (float*)(ws + 210767872);          // 4,194,304
  float* SA   = (float*)(ws + 214962176);          // 262,144
  float* SB   = (float*)(ws + 215224320);          // 262,144
  float* hsc  = (float*)(ws + 215486464);          // 262,144  (total ~215.7 MB)

  k_wconv<<<2048, 256, 0, stream>>>(wf, bfo, wb, bb, Wbm, bias);
  k_xpose<<<dim3(SEQ / 64, DIN / 64, BATCH), 256, 0, stream>>>(x, xT);
  k_gemm<<<dim3(ECH / 128, SEQ / 128, BATCH), 256, 0, stream>>>(xT, Wbm, bias, hg);
  k_scan1<<<dim3(NCHNK, 2, BATCH), 256, 0, stream>>>(hg, Asum, Bsum);
  k_scan2a<<<dim3(NSC, 16), 256, 0, stream>>>(Asum, Bsum, SA, SB);
  k_scan2b<<<16, 256, 0, stream>>>(SA, SB, hsc);
  k_scan2c<<<dim3(NSC, 16), 256, 0, stream>>>(Asum, Bsum, hsc, hin);
  k_scan3<<<dim3(NCHNK, 2, BATCH), 256, 0, stream>>>(hg, hin, out);
}

// Round 3
// 381.861 us; speedup vs baseline: 1.0806x; 1.0142x over previous
//
#include <hip/hip_runtime.h>

#define BATCH 8
#define DIN   512
#define SEQ   8192
#define ECH   1024   // concatenated conv output channels (fore 512 | back 512)
#define HCH   256    // per-direction hidden channels
#define CL    32     // scan chunk length
#define NCHNK (SEQ / CL)   // 256 chunks per row
#define NSC   16           // superchunks (16 chunks each)

typedef __bf16 bf16;
typedef __bf16 bf16x8 __attribute__((ext_vector_type(8)));
typedef __bf16 bf16x4 __attribute__((ext_vector_type(4)));
typedef float  floatx4 __attribute__((ext_vector_type(4)));

__device__ __forceinline__ void async_ld16(void* lds, const void* g) {
  __builtin_amdgcn_global_load_lds(
      (const __attribute__((address_space(1))) unsigned int*)g,
      (__attribute__((address_space(3))) unsigned int*)lds, 16, 0, 0);
}

__device__ __forceinline__ float bits2f(unsigned u) {
  return __builtin_bit_cast(float, u);
}

// minGRU step: a = sigmoid(-g), bt = sigmoid(g) * (h>=0 ? 1+h : exp(h))
__device__ __forceinline__ void gru_ab(unsigned v, float& a, float& bt) {
  float hh = bits2f(v << 16);
  float g  = bits2f(v & 0xffff0000u);
  float eg = __expf(-g);
  float sg = 1.f / (1.f + eg);   // sigmoid(g)
  a = eg * sg;                    // sigmoid(-g)
  float gv = hh >= 0.f ? 1.f + hh : __expf(hh);
  bt = sg * gv;
}

// ---------------------------------------------------------------------------
// Kernel 1: convert/permute weights to bf16, channel-interleaved (h,gate) pairs.
// ---------------------------------------------------------------------------
__global__ void k_wconv(const float* __restrict__ wf, const float* __restrict__ bfo,
                        const float* __restrict__ wb, const float* __restrict__ bb,
                        bf16* __restrict__ Wb, float* __restrict__ bias) {
  int idx = blockIdx.x * 256 + threadIdx.x;
  if (idx < ECH * DIN) {
    int n = idx >> 9, d = idx & 511;
    int dir = n >> 9, r = n & 511, e = r >> 1, isg = r & 1;
    int s = e + (isg ? HCH : 0);
    const float* w = dir ? wb : wf;
    Wb[idx] = (bf16)w[s * DIN + d];
  }
  if (idx < ECH) {
    int dir = idx >> 9, r = idx & 511, e = r >> 1, isg = r & 1;
    int s = e + (isg ? HCH : 0);
    bias[idx] = (dir ? bb : bfo)[s];
  }
}

// ---------------------------------------------------------------------------
// Kernel 2: tiled transpose + convert  x[b,d,l] fp32 -> xT[b,l,d] bf16
// ---------------------------------------------------------------------------
__global__ void k_xpose(const float* __restrict__ x, bf16* __restrict__ xT) {
  __shared__ float T[64 * 65];
  int t = threadIdx.x;
  int l0 = blockIdx.x * 64;
  int d0 = blockIdx.y * 64;
  int b  = blockIdx.z;
  const float* xb = x + (size_t)b * DIN * SEQ;
#pragma unroll
  for (int p = 0; p < 4; ++p) {
    int dl = (t >> 4) + p * 16;
    int l4 = (t & 15) * 4;
    float4 v = *(const float4*)(xb + (size_t)(d0 + dl) * SEQ + l0 + l4);
    T[dl * 65 + l4 + 0] = v.x;
    T[dl * 65 + l4 + 1] = v.y;
    T[dl * 65 + l4 + 2] = v.z;
    T[dl * 65 + l4 + 3] = v.w;
  }
  __syncthreads();
  bf16* xTb = xT + (size_t)b * SEQ * DIN;
#pragma unroll
  for (int p = 0; p < 2; ++p) {
    int ll = (t >> 3) + p * 32;
    int d8 = (t & 7) * 8;
    bf16x8 h;
#pragma unroll
    for (int j = 0; j < 8; ++j) h[j] = (bf16)T[(d8 + j) * 65 + ll];
    *(bf16x8*)(xTb + (size_t)(l0 + ll) * DIN + d0 + d8) = h;
  }
}

// ---------------------------------------------------------------------------
// Kernel 3: bf16 MFMA GEMM  hg[b,l,n] = sum_d xT[b,l,d] * Wb[n,d] + bias[n]
// 128x128 tile, BK=64, 4 waves, 16x16x32 frags. XOR-swizzled LDS, XCD remap.
// Fused epilogue: per-chunk minGRU affine composition (A,B) straight from the
// C-tile in LDS (replaces the old k_scan1 global re-read).
// ---------------------------------------------------------------------------
__launch_bounds__(256, 4)
__global__ void k_gemm(const bf16* __restrict__ xT, const bf16* __restrict__ Wb,
                       const float* __restrict__ bias, bf16* __restrict__ hg,
                       float* __restrict__ Asum, float* __restrict__ Bsum) {
  __shared__ bf16 lds[16896];       // staging: As[128][64]|Bs[128][64]; epilogue: Cs[128][132]
  bf16* As = lds;
  bf16* Bs = lds + 8192;

  int t = threadIdx.x;
  int lane = t & 63, wave = t >> 6;

  // XCD-locality remap: all 8 n-tiles of one l-tile on one XCD.
  int lin = blockIdx.x + 8 * blockIdx.y;   // 0..511
  int xcd = lin & 7;
  int seq = lin >> 3;                      // 0..63
  int ltile = xcd + 8 * (seq >> 3);        // 0..63
  int ntile = seq & 7;
  int n0 = ntile * 128;
  int l0 = ltile * 128;
  int b  = blockIdx.z;

  int l15 = lane & 15, quad = lane >> 4;
  int wm = wave >> 1, wn = wave & 1;
  int mb = wm * 64, nb = wn * 64;

  const bf16* gA = xT + ((size_t)b * SEQ + l0) * DIN;
  const bf16* gB = Wb + (size_t)n0 * DIN;

  int srow = wave * 32 + (lane >> 3);                       // + q*8 later
  int scol = (((lane & 7) ^ (lane >> 3)) * 8);              // XOR-swizzled source col

  floatx4 acc[4][4];
#pragma unroll
  for (int i = 0; i < 4; ++i)
#pragma unroll
    for (int j = 0; j < 4; ++j) acc[i][j] = (floatx4){0.f, 0.f, 0.f, 0.f};

  for (int kt = 0; kt < DIN / 64; ++kt) {
    int k0 = kt * 64;
#pragma unroll
    for (int q = 0; q < 4; ++q) {
      async_ld16(As + (wave * 32 + q * 8) * 64,
                 gA + (size_t)(srow + q * 8) * DIN + k0 + scol);
      async_ld16(Bs + (wave * 32 + q * 8) * 64,
                 gB + (size_t)(srow + q * 8) * DIN + k0 + scol);
    }
    __syncthreads();
#pragma unroll
    for (int kk = 0; kk < 64; kk += 32) {
      int rsw = l15 & 7;
      bf16x8 af[4], bfr[4];
#pragma unroll
      for (int i = 0; i < 4; ++i)
        af[i] = *(const bf16x8*)(As + (mb + i * 16 + l15) * 64 +
                                 (((kk >> 3) + quad) ^ rsw) * 8);
#pragma unroll
      for (int i = 0; i < 4; ++i)
        bfr[i] = *(const bf16x8*)(Bs + (nb + i * 16 + l15) * 64 +
                                  (((kk >> 3) + quad) ^ rsw) * 8);
#pragma unroll
      for (int mi = 0; mi < 4; ++mi)
#pragma unroll
        for (int ni = 0; ni < 4; ++ni)
          acc[mi][ni] = __builtin_amdgcn_mfma_f32_16x16x32_bf16(
              af[mi], bfr[ni], acc[mi][ni], 0, 0, 0);
    }
    __syncthreads();
  }

  // epilogue: bias add, pack to bf16 in LDS (stride 132 breaks conflicts), store
  float bb4[4];
#pragma unroll
  for (int ni = 0; ni < 4; ++ni) bb4[ni] = bias[n0 + nb + ni * 16 + l15];
  bf16* Cs = lds;  // [128][132]
#pragma unroll
  for (int mi = 0; mi < 4; ++mi)
#pragma unroll
    for (int ni = 0; ni < 4; ++ni)
#pragma unroll
      for (int r = 0; r < 4; ++r) {
        int row = mb + mi * 16 + quad * 4 + r;
        int col = nb + ni * 16 + l15;
        Cs[row * 132 + col] = (bf16)(acc[mi][ni][r] + bb4[ni]);
      }
  __syncthreads();
  bf16* hgb = hg + ((size_t)b * SEQ + l0) * ECH + n0;
#pragma unroll
  for (int p = 0; p < 8; ++p) {
    int row = p * 16 + (t >> 4);
    int seg = t & 15;
    *(bf16x8*)(hgb + (size_t)row * ECH + seg * 8) =
        *(const bf16x8*)(Cs + row * 132 + seg * 8);
  }

  // fused per-chunk minGRU composition (replaces k_scan1)
  // wave = chunk within tile (4 chunks of 32), lane = e-pair within tile (64)
  {
    int dirn = ntile >> 2;               // n0 >> 9
    int c = wave, el = lane;
    float A = 1.f, Bc = 0.f;
#pragma unroll 8
    for (int i = 0; i < CL; ++i) {
      int row = c * CL + (dirn ? (CL - 1 - i) : i);
      unsigned v = *(const unsigned*)(Cs + row * 132 + 2 * el);
      float a, bt;
      gru_ab(v, a, bt);
      A *= a;
      Bc = a * Bc + bt;
    }
    int chunkg = ltile * 4 + c;
    int eg = ((n0 & 511) >> 1) + el;
    size_t o = ((size_t)(b * 2 + dirn) * NCHNK + chunkg) * 256 + eg;
    Asum[o] = A;
    Bsum[o] = Bc;
  }
}

// ---------------------------------------------------------------------------
// Kernel 5a: per-superchunk (16 chunks) composition. 256 blocks x 256 thr.
// ---------------------------------------------------------------------------
__global__ void k_scan2a(const float* __restrict__ Asum, const float* __restrict__ Bsum,
                         float* __restrict__ SA, float* __restrict__ SB) {
  int e = threadIdx.x, sc = blockIdx.x, row2 = blockIdx.y, dir = row2 & 1;
  size_t base = (size_t)row2 * NCHNK;
  float Acc = 1.f, Bcc = 0.f;
#pragma unroll
  for (int i = 0; i < 16; ++i) {
    int c = sc * 16 + (dir ? 15 - i : i);
    size_t o = (base + c) * 256 + e;
    float a = Asum[o], bv = Bsum[o];
    Acc = a * Acc;
    Bcc = a * Bcc + bv;
  }
  size_t so = ((size_t)row2 * NSC + sc) * 256 + e;
  SA[so] = Acc;
  SB[so] = Bcc;
}

// ---------------------------------------------------------------------------
// Kernel 5b: scan the 16 superchunks per row. 16 blocks x 256 thr.
// ---------------------------------------------------------------------------
__global__ void k_scan2b(const float* __restrict__ SA, const float* __restrict__ SB,
                         float* __restrict__ hsc) {
  int e = threadIdx.x, row2 = blockIdx.x, dir = row2 & 1;
  float h = 0.f;
  for (int i = 0; i < NSC; ++i) {
    int sc = dir ? NSC - 1 - i : i;
    size_t o = ((size_t)row2 * NSC + sc) * 256 + e;
    hsc[o] = h;
    h = SA[o] * h + SB[o];
  }
}

// ---------------------------------------------------------------------------
// Kernel 5c: distribute carries to every chunk. 256 blocks x 256 thr.
// ---------------------------------------------------------------------------
__global__ void k_scan2c(const float* __restrict__ Asum, const float* __restrict__ Bsum,
                         const float* __restrict__ hsc, float* __restrict__ hin) {
  int e = threadIdx.x, sc = blockIdx.x, row2 = blockIdx.y, dir = row2 & 1;
  float h = hsc[((size_t)row2 * NSC + sc) * 256 + e];
#pragma unroll
  for (int i = 0; i < 16; ++i) {
    int c = sc * 16 + (dir ? 15 - i : i);
    size_t o = ((size_t)row2 * NCHNK + c) * 256 + e;
    hin[o] = h;
    h = Asum[o] * h + Bsum[o];
  }
}

// ---------------------------------------------------------------------------
// Kernel 6: recompute local scan with carry-in, transpose via LDS (stride 33),
// write out[b, dir*256+e, l] as coalesced float4.
// ---------------------------------------------------------------------------
__global__ void k_scan3(const bf16* __restrict__ hg, const float* __restrict__ hin,
                        float* __restrict__ out) {
  __shared__ float T[256 * 33];
  int t = threadIdx.x;
  int chunk = blockIdx.x, dir = blockIdx.y, b = blockIdx.z;
  const bf16* hb = hg + (size_t)b * SEQ * ECH + dir * 512 + 2 * t;
  float h = hin[((size_t)(b * 2 + dir) * NCHNK + chunk) * 256 + t];
  int lbase = chunk * CL;
#pragma unroll 8
  for (int i = 0; i < CL; ++i) {
    int ll = dir ? (CL - 1 - i) : i;
    unsigned v = *(const unsigned*)(hb + (size_t)(lbase + ll) * ECH);
    float a, bt;
    gru_ab(v, a, bt);
    h = a * h + bt;
    T[t * 33 + ll] = h;
  }
  __syncthreads();
  float* ob = out + ((size_t)b * 512 + dir * 256) * SEQ + lbase;
#pragma unroll
  for (int p = 0; p < 8; ++p) {
    int row = p * 32 + (t >> 3);   // e channel
    int c4 = (t & 7) * 4;          // l within chunk
    float4 v4;
    v4.x = T[row * 33 + c4 + 0];
    v4.y = T[row * 33 + c4 + 1];
    v4.z = T[row * 33 + c4 + 2];
    v4.w = T[row * 33 + c4 + 3];
    *(float4*)(ob + (size_t)row * SEQ + c4) = v4;
  }
}

// ---------------------------------------------------------------------------
extern "C" void kernel_launch(void* const* d_in, const int* in_sizes, int n_in,
                              void* d_out, int out_size, void* d_ws, size_t ws_size,
                              hipStream_t stream) {
  const float* x   = (const float*)d_in[0];
  const float* wf  = (const float*)d_in[1];
  const float* bfo = (const float*)d_in[2];
  const float* wb  = (const float*)d_in[3];
  const float* bb  = (const float*)d_in[4];
  float* out = (float*)d_out;
  char* ws = (char*)d_ws;

  // workspace layout (bytes):
  bf16*  xT   = (bf16*)(ws);                       // 67,108,864
  bf16*  hg   = (bf16*)(ws + 67108864);            // 134,217,728
  bf16*  Wbm  = (bf16*)(ws + 201326592);           // 1,048,576
  float* bias = (float*)(ws + 202375168);          // 4,096
  float* Asum = (float*)(ws + 202379264);          // 4,194,304
  float* Bsum = (float*)(ws + 206573568);          // 4,194,304
  float* hin  = (float*)(ws + 210767872);          // 4,194,304
  float* SA   = (float*)(ws + 214962176);          // 262,144
  float* SB   = (float*)(ws + 215224320);          // 262,144
  float* hsc  = (float*)(ws + 215486464);          // 262,144  (total ~215.7 MB)

  k_wconv<<<2048, 256, 0, stream>>>(wf, bfo, wb, bb, Wbm, bias);
  k_xpose<<<dim3(SEQ / 64, DIN / 64, BATCH), 256, 0, stream>>>(x, xT);
  k_gemm<<<dim3(ECH / 128, SEQ / 128, BATCH), 256, 0, stream>>>(xT, Wbm, bias, hg,
                                                                Asum, Bsum);
  k_scan2a<<<dim3(NSC, 16), 256, 0, stream>>>(Asum, Bsum, SA, SB);
  k_scan2b<<<16, 256, 0, stream>>>(SA, SB, hsc);
  k_scan2c<<<dim3(NSC, 16), 256, 0, stream>>>(Asum, Bsum, hsc, hin);
  k_scan3<<<dim3(NCHNK, 2, BATCH), 256, 0, stream>>>(hg, hin, out);
}